// Round 7
// baseline (62.007 us; speedup 1.0000x reference)
//
#include <hip/hip_runtime.h>

#define BATCH   4096
#define IN_DIM  512
#define OUT_DIM 32
#define CH      8     // channels per block
#define NB      64    // batches per X group
#define NGROUP  4     // X groups per block
#define CGRID   (IN_DIM / CH)            // 64
#define BGRID   (BATCH / (NB * NGROUP))  // 16

typedef float f32x4 __attribute__((ext_vector_type(4)));

__global__ __launch_bounds__(256) void simplex_interp_wavepriv(
    const float* __restrict__ X,       // [BATCH, IN_DIM, 4]
    const float* __restrict__ params,  // [IN_DIM, 16, OUT_DIM]
    float* __restrict__ out)           // [BATCH, IN_DIM, OUT_DIM]
{
    __shared__ float lds_p[CH * 16 * OUT_DIM];   // 16 KB params tile
    // wave-private X tiles: [buf][wave][local batch i][8 ch * 4 floats]
    __shared__ float lds_x[2][4][16][32];        // 16 KB total

    const int tid  = threadIdx.x;
    const int w    = tid >> 6;           // wave id 0..3
    const int lane = tid & 63;
    const int cg   = blockIdx.x & (CGRID - 1);
    const int bg   = blockIdx.x >> 6;    // / CGRID
    const int g0   = cg * CH;
    const int b0   = bg * (NB * NGROUP);

    // ---- stage params tile: 16 KB contiguous, once per block ----
    {
        const float* src = params + (size_t)g0 * (16 * OUT_DIM);
        #pragma unroll
        for (int k = 0; k < 4; ++k) {
            const int off = (k * 256 + tid) * 4;
            *reinterpret_cast<f32x4*>(&lds_p[off]) =
                *reinterpret_cast<const f32x4*>(src + off);
        }
    }

    // ---- wave-private X staging: lane stages chunks (i0,p0) and (i0+8,p0) ----
    const int i0 = lane >> 3;      // 0..7
    const int p0 = lane & 7;       // channel offset within the 128B batch row

    f32x4 ra, rb;
    auto load_x = [&](int grp) {
        const int bbase = b0 + grp * NB + w;        // this wave's batches: bbase + 4*i
        const size_t o0 = ((size_t)(bbase + 4 * i0)       * IN_DIM + g0 + p0) * 4;
        const size_t o1 = ((size_t)(bbase + 4 * (i0 + 8)) * IN_DIM + g0 + p0) * 4;
        ra = __builtin_nontemporal_load(reinterpret_cast<const f32x4*>(X + o0));
        rb = __builtin_nontemporal_load(reinterpret_cast<const f32x4*>(X + o1));
    };
    auto write_x = [&](int buf) {
        *reinterpret_cast<f32x4*>(&lds_x[buf][w][i0][p0 * 4])     = ra;
        *reinterpret_cast<f32x4*>(&lds_x[buf][w][i0 + 8][p0 * 4]) = rb;
    };

    load_x(0);
    write_x(0);
    __syncthreads();   // params visibility (also covers our own X writes)

    const int c   = (lane >> 3) & 7;   // local channel
    const int sub = lane & 7;          // float4 slice of the 32 outputs
    const int g   = g0 + c;

    const float* ldsc = &lds_p[c * (16 * OUT_DIM) + sub * 4];
    const f32x4  p15  = *reinterpret_cast<const f32x4*>(ldsc + 15 * OUT_DIM);

    int buf = 0;
    for (int grp = 0; grp < NGROUP; ++grp) {
        // prefetch next group's X into registers (lands during the 16 iters)
        if (grp + 1 < NGROUP) load_x(grp + 1);

        const int bbase = b0 + grp * NB + w;
        #pragma unroll 4
        for (int i = 0; i < 16; ++i) {
            const f32x4 xv = *reinterpret_cast<const f32x4*>(&lds_x[buf][w][i][c * 4]);

            // ---- 5-comparator sort network, ascending (branchless) ----
            float v0 = xv.x, v1 = xv.y, v2 = xv.z, v3 = xv.w;
            int   j0 = 0,    j1 = 1,    j2 = 2,    j3 = 3;
#define CSWAP(va, vb, ia, ib)                                            \
            {                                                            \
                bool lt = (vb) < (va);                                   \
                float tv = (va); (va) = lt ? (vb) : (va); (vb) = lt ? tv : (vb); \
                int   ti = (ia); (ia) = lt ? (ib) : (ia); (ib) = lt ? ti : (ib); \
            }
            CSWAP(v0, v1, j0, j1)
            CSWAP(v2, v3, j2, j3)
            CSWAP(v0, v2, j0, j2)
            CSWAP(v1, v3, j1, j3)
            CSWAP(v1, v2, j1, j2)
#undef CSWAP

            const float c0f = v0;
            const float c1f = v1 - v0;
            const float c2f = v2 - v1;
            const float c3f = v3 - v2;

            const int idx3 = (1 << j3);
            const int idx2 = idx3 + (1 << j2);
            const int idx1 = idx2 + (1 << j1);

            // LDS gathers: 8-lane groups read full 128-B rows (broadcast, conflict-free)
            const f32x4 q1 = *reinterpret_cast<const f32x4*>(ldsc + idx1 * OUT_DIM);
            const f32x4 q2 = *reinterpret_cast<const f32x4*>(ldsc + idx2 * OUT_DIM);
            const f32x4 q3 = *reinterpret_cast<const f32x4*>(ldsc + idx3 * OUT_DIM);

            const f32x4 acc = c0f * p15 + c1f * q1 + c2f * q2 + c3f * q3;

            // plain store: wave writes 1 KB contiguous; never awaited mid-loop
            *reinterpret_cast<f32x4*>(
                out + ((size_t)(bbase + 4 * i) * IN_DIM + g) * OUT_DIM + sub * 4) = acc;
        }

        // wave-private handoff: only waits on our own prefetch loads
        if (grp + 1 < NGROUP) {
            write_x(buf ^ 1);
            buf ^= 1;
        }
    }
}

extern "C" void kernel_launch(void* const* d_in, const int* in_sizes, int n_in,
                              void* d_out, int out_size, void* d_ws, size_t ws_size,
                              hipStream_t stream) {
    const float* X      = (const float*)d_in[0];
    const float* params = (const float*)d_in[1];
    float*       out    = (float*)d_out;

    const int nblocks = CGRID * BGRID;   // 64 * 16 = 1024
    simplex_interp_wavepriv<<<nblocks, 256, 0, stream>>>(X, params, out);
}

// Round 8
// 54.448 us; speedup vs baseline: 1.1388x; 1.1388x over previous
//
#include <hip/hip_runtime.h>

#define BATCH   4096
#define IN_DIM  512
#define OUT_DIM 32
#define CH      8     // channels per block
#define NB      64    // batches per X group
#define NGROUP  4     // X groups per block
#define CGRID   (IN_DIM / CH)            // 64
#define BGRID   (BATCH / (NB * NGROUP))  // 16

typedef float f32x4 __attribute__((ext_vector_type(4)));

__global__ __launch_bounds__(256) void simplex_interp_dbuf(
    const float* __restrict__ X,       // [BATCH, IN_DIM, 4]
    const float* __restrict__ params,  // [IN_DIM, 16, OUT_DIM]
    float* __restrict__ out)           // [BATCH, IN_DIM, OUT_DIM]
{
    __shared__ float lds_p[CH * 16 * OUT_DIM];   // 16 KB params tile
    __shared__ float lds_x[2][NB][CH * 4];       // 2 x 8 KB X tiles

    const int tid = threadIdx.x;
    const int cg  = blockIdx.x & (CGRID - 1);
    const int bg  = blockIdx.x >> 6;             // / CGRID
    const int g0  = cg * CH;
    const int b0  = bg * (NB * NGROUP);

    // ---- stage params tile: 16 KB contiguous, once per block ----
    {
        const float* src = params + (size_t)g0 * (16 * OUT_DIM);
        #pragma unroll
        for (int k = 0; k < 4; ++k) {
            const int off = (k * 256 + tid) * 4;
            *reinterpret_cast<f32x4*>(&lds_p[off]) =
                *reinterpret_cast<const f32x4*>(src + off);
        }
    }

    // ---- block-shared X staging (keeps waves coupled): thread stages 2 chunks ----
    const int xlb0  = tid >> 3;            // local batch 0..31
    const int xpos0 = tid & 7;
    const int xlb1  = (256 + tid) >> 3;    // local batch 32..63
    const int xpos1 = xpos0;

    f32x4 ra, rb;
    auto load_x = [&](int grp) {
        const size_t base = ((size_t)(b0 + grp * NB) * IN_DIM + g0) * 4;
        ra = __builtin_nontemporal_load(
            reinterpret_cast<const f32x4*>(X + base + (size_t)xlb0 * (IN_DIM * 4) + xpos0 * 4));
        rb = __builtin_nontemporal_load(
            reinterpret_cast<const f32x4*>(X + base + (size_t)xlb1 * (IN_DIM * 4) + xpos1 * 4));
    };
    auto write_x = [&](int buf) {
        *reinterpret_cast<f32x4*>(&lds_x[buf][xlb0][xpos0 * 4]) = ra;
        *reinterpret_cast<f32x4*>(&lds_x[buf][xlb1][xpos1 * 4]) = rb;
    };

    load_x(0);
    write_x(0);
    __syncthreads();   // params + group-0 X visible

    const int bq  = tid >> 6;          // wave id: batch phase within iteration
    const int c   = (tid >> 3) & 7;    // local channel
    const int sub = tid & 7;           // float4 slice of the 32 outputs
    const int g   = g0 + c;

    const float* ldsc = &lds_p[c * (16 * OUT_DIM) + sub * 4];
    const f32x4  p15  = *reinterpret_cast<const f32x4*>(ldsc + 15 * OUT_DIM);

    int buf = 0;
    for (int grp = 0; grp < NGROUP; ++grp) {
        // prefetch next group's X into registers (lands during the 16 iters)
        if (grp + 1 < NGROUP) load_x(grp + 1);

        const int bbase = b0 + grp * NB;
        #pragma unroll 4
        for (int i = 0; i < NB / 4; ++i) {
            const int lb = i * 4 + bq;
            const f32x4 xv = *reinterpret_cast<const f32x4*>(&lds_x[buf][lb][c * 4]);

            // ---- 5-comparator sort network, ascending (branchless) ----
            float v0 = xv.x, v1 = xv.y, v2 = xv.z, v3 = xv.w;
            int   j0 = 0,    j1 = 1,    j2 = 2,    j3 = 3;
#define CSWAP(va, vb, ia, ib)                                            \
            {                                                            \
                bool lt = (vb) < (va);                                   \
                float tv = (va); (va) = lt ? (vb) : (va); (vb) = lt ? tv : (vb); \
                int   ti = (ia); (ia) = lt ? (ib) : (ia); (ib) = lt ? ti : (ib); \
            }
            CSWAP(v0, v1, j0, j1)
            CSWAP(v2, v3, j2, j3)
            CSWAP(v0, v2, j0, j2)
            CSWAP(v1, v3, j1, j3)
            CSWAP(v1, v2, j1, j2)
#undef CSWAP

            const float c0f = v0;
            const float c1f = v1 - v0;
            const float c2f = v2 - v1;
            const float c3f = v3 - v2;

            const int idx3 = (1 << j3);
            const int idx2 = idx3 + (1 << j2);
            const int idx1 = idx2 + (1 << j1);

            // LDS gathers: 8-lane groups read full 128-B rows
            const f32x4 q1 = *reinterpret_cast<const f32x4*>(ldsc + idx1 * OUT_DIM);
            const f32x4 q2 = *reinterpret_cast<const f32x4*>(ldsc + idx2 * OUT_DIM);
            const f32x4 q3 = *reinterpret_cast<const f32x4*>(ldsc + idx3 * OUT_DIM);

            const f32x4 acc = c0f * p15 + c1f * q1 + c2f * q2 + c3f * q3;

            // plain store through L2; wave writes 1 KB contiguous
            *reinterpret_cast<f32x4*>(
                out + ((size_t)(bbase + lb) * IN_DIM + g) * OUT_DIM + sub * 4) = acc;
        }

        // double-buffer handoff: write the idle buffer, ONE barrier, swap
        if (grp + 1 < NGROUP) {
            write_x(buf ^ 1);
            __syncthreads();
            buf ^= 1;
        }
    }
}

extern "C" void kernel_launch(void* const* d_in, const int* in_sizes, int n_in,
                              void* d_out, int out_size, void* d_ws, size_t ws_size,
                              hipStream_t stream) {
    const float* X      = (const float*)d_in[0];
    const float* params = (const float*)d_in[1];
    float*       out    = (float*)d_out;

    const int nblocks = CGRID * BGRID;   // 64 * 16 = 1024
    simplex_interp_dbuf<<<nblocks, 256, 0, stream>>>(X, params, out);
}